// Round 1
// baseline (554.947 us; speedup 1.0000x reference)
//
#include <hip/hip_runtime.h>
#include <hip/hip_bf16.h>

#define N_NODES 65536
#define D_FEAT  64
#define N_EDGES 1048576

// One 64-lane wave per edge. Lane d handles feature d.
// gather x[col][d] (coalesced 256B), scale, atomicAdd into out[row][d].
__global__ __launch_bounds__(256) void spmm_atomic_kernel(
    const float* __restrict__ x,
    const int*   __restrict__ rows,
    const int*   __restrict__ cols,
    const float* __restrict__ vals,
    float*       __restrict__ out,
    int n_edges)
{
    const int gid  = blockIdx.x * blockDim.x + threadIdx.x;
    const int edge = gid >> 6;          // wave index == edge index
    const int lane = threadIdx.x & 63;
    if (edge >= n_edges) return;

    // Wave-uniform scalar loads (broadcast via cache).
    const int   r = rows[edge];
    const int   c = cols[edge];
    const float v = vals[edge];

    const float g = v * x[(size_t)c * D_FEAT + lane];
    atomicAdd(&out[(size_t)r * D_FEAT + lane], g);
}

extern "C" void kernel_launch(void* const* d_in, const int* in_sizes, int n_in,
                              void* d_out, int out_size, void* d_ws, size_t ws_size,
                              hipStream_t stream) {
    const float* x1      = (const float*)d_in[0];
    const float* x2      = (const float*)d_in[1];
    const int*   a1_rows = (const int*)  d_in[2];
    const int*   a1_cols = (const int*)  d_in[3];
    const float* a1_vals = (const float*)d_in[4];
    const int*   a2_rows = (const int*)  d_in[5];
    const int*   a2_cols = (const int*)  d_in[6];
    const float* a2_vals = (const float*)d_in[7];

    float* out1 = (float*)d_out;
    float* out2 = out1 + (size_t)N_NODES * D_FEAT;

    // d_out is poisoned to 0xAA before every timed call — zero it first.
    hipMemsetAsync(d_out, 0, (size_t)out_size * sizeof(float), stream);

    const int threads = 256;                       // 4 waves/block = 4 edges/block
    const int blocks  = (N_EDGES * 64 + threads - 1) / threads;

    spmm_atomic_kernel<<<blocks, threads, 0, stream>>>(
        x1, a1_rows, a1_cols, a1_vals, out1, N_EDGES);
    spmm_atomic_kernel<<<blocks, threads, 0, stream>>>(
        x2, a2_rows, a2_cols, a2_vals, out2, N_EDGES);
}

// Round 2
// 508.518 us; speedup vs baseline: 1.0913x; 1.0913x over previous
//
#include <hip/hip_runtime.h>
#include <hip/hip_bf16.h>

#define N_NODES 65536
#define D_FEAT  64
#define N_EDGES 1048576

// ---------------- Phase 1: count edges per row ----------------
__global__ __launch_bounds__(256) void count_kernel(
    const int* __restrict__ rows, int* __restrict__ cnt, int n)
{
    int i = blockIdx.x * blockDim.x + threadIdx.x;
    if (i < n) atomicAdd(&cnt[rows[i]], 1);
}

// ---------------- Phase 2: exclusive scan of 65536 counts ----------------
// Single block, 1024 threads, each thread owns 64 consecutive rows.
// cnt_cursor holds counts on entry; on exit it holds the exclusive offsets
// (to serve as the scatter cursor). offsets[] gets the same values plus
// offsets[N_NODES] = total.
__global__ __launch_bounds__(1024) void scan_kernel(
    int* __restrict__ cnt_cursor, int* __restrict__ offsets)
{
    const int t = threadIdx.x;
    __shared__ int s[1024];
    const int base_i = t * 64;

    int total = 0;
    for (int i = 0; i < 64; ++i) total += cnt_cursor[base_i + i];
    s[t] = total;
    __syncthreads();

    // Hillis-Steele inclusive scan over 1024 per-thread totals.
    for (int off = 1; off < 1024; off <<= 1) {
        int add = (t >= off) ? s[t - off] : 0;
        __syncthreads();
        s[t] += add;
        __syncthreads();
    }

    int run = s[t] - total;   // exclusive prefix for this thread's chunk
    for (int i = 0; i < 64; ++i) {
        int c = cnt_cursor[base_i + i];
        offsets[base_i + i]    = run;
        cnt_cursor[base_i + i] = run;
        run += c;
    }
    if (t == 1023) offsets[N_NODES] = s[1023];
}

// ---------------- Phase 3: scatter edges into row-sorted order ----------------
__global__ __launch_bounds__(256) void scatter_kernel(
    const int* __restrict__ rows, const int* __restrict__ cols,
    const float* __restrict__ vals,
    int* __restrict__ cursor, float2* __restrict__ perm, int n)
{
    int i = blockIdx.x * blockDim.x + threadIdx.x;
    if (i < n) {
        int r = rows[i];
        int pos = atomicAdd(&cursor[r], 1);
        perm[pos] = make_float2(vals[i], __int_as_float(cols[i]));
    }
}

// ---------------- Phase 4: CSR SpMM, one wave per row, no atomics ----------------
__global__ __launch_bounds__(256) void csr_spmm_kernel(
    const int* __restrict__ offsets, const float2* __restrict__ perm,
    const float* __restrict__ x, float* __restrict__ out)
{
    const int wave = (blockIdx.x * blockDim.x + threadIdx.x) >> 6;
    const int lane = threadIdx.x & 63;
    if (wave >= N_NODES) return;

    int e   = offsets[wave];
    int end = offsets[wave + 1];
    float acc = 0.f;

    // 2 edges per iteration -> 2 independent gathers in flight.
    for (; e + 1 < end; e += 2) {
        float2 p0 = perm[e];
        float2 p1 = perm[e + 1];
        int c0 = __float_as_int(p0.y);
        int c1 = __float_as_int(p1.y);
        float g0 = x[(size_t)c0 * D_FEAT + lane];
        float g1 = x[(size_t)c1 * D_FEAT + lane];
        acc = fmaf(p0.x, g0, acc);
        acc = fmaf(p1.x, g1, acc);
    }
    if (e < end) {
        float2 p = perm[e];
        int c = __float_as_int(p.y);
        acc = fmaf(p.x, x[(size_t)c * D_FEAT + lane], acc);
    }
    out[(size_t)wave * D_FEAT + lane] = acc;
}

// ---------------- Fallback: round-1 atomic kernel (if ws too small) ----------------
__global__ __launch_bounds__(256) void spmm_atomic_kernel(
    const float* __restrict__ x,
    const int*   __restrict__ rows,
    const int*   __restrict__ cols,
    const float* __restrict__ vals,
    float*       __restrict__ out,
    int n_edges)
{
    const int gid  = blockIdx.x * blockDim.x + threadIdx.x;
    const int edge = gid >> 6;
    const int lane = threadIdx.x & 63;
    if (edge >= n_edges) return;
    const int   r = rows[edge];
    const int   c = cols[edge];
    const float v = vals[edge];
    atomicAdd(&out[(size_t)r * D_FEAT + lane], v * x[(size_t)c * D_FEAT + lane]);
}

extern "C" void kernel_launch(void* const* d_in, const int* in_sizes, int n_in,
                              void* d_out, int out_size, void* d_ws, size_t ws_size,
                              hipStream_t stream) {
    const float* x1      = (const float*)d_in[0];
    const float* x2      = (const float*)d_in[1];
    const int*   a1_rows = (const int*)  d_in[2];
    const int*   a1_cols = (const int*)  d_in[3];
    const float* a1_vals = (const float*)d_in[4];
    const int*   a2_rows = (const int*)  d_in[5];
    const int*   a2_cols = (const int*)  d_in[6];
    const float* a2_vals = (const float*)d_in[7];

    float* out1 = (float*)d_out;
    float* out2 = out1 + (size_t)N_NODES * D_FEAT;

    // Workspace layout (all 4-byte units; perm arrays 8-byte aligned).
    const int OFF_PAD = 65544;                 // 65537 rounded up, keeps alignment
    int* cur1 = (int*)d_ws;                    // 65536
    int* cur2 = cur1 + N_NODES;                // 65536
    int* off1 = cur2 + N_NODES;                // OFF_PAD
    int* off2 = off1 + OFF_PAD;                // OFF_PAD
    float2* perm1 = (float2*)(off2 + OFF_PAD); // N_EDGES float2
    float2* perm2 = perm1 + N_EDGES;

    size_t needed = ((size_t)(2 * N_NODES + 2 * OFF_PAD)) * 4
                  + 2 * (size_t)N_EDGES * sizeof(float2);

    if (ws_size < needed) {
        // Fallback: atomic scatter version (round-1 behavior).
        hipMemsetAsync(d_out, 0, (size_t)out_size * sizeof(float), stream);
        const int blocks = (N_EDGES * 64 + 255) / 256;
        spmm_atomic_kernel<<<blocks, 256, 0, stream>>>(x1, a1_rows, a1_cols, a1_vals, out1, N_EDGES);
        spmm_atomic_kernel<<<blocks, 256, 0, stream>>>(x2, a2_rows, a2_cols, a2_vals, out2, N_EDGES);
        return;
    }

    // Zero both count arrays (contiguous) — ws is poisoned before every call.
    hipMemsetAsync(cur1, 0, (size_t)2 * N_NODES * sizeof(int), stream);

    const int eblocks = (N_EDGES + 255) / 256;

    count_kernel<<<eblocks, 256, 0, stream>>>(a1_rows, cur1, N_EDGES);
    count_kernel<<<eblocks, 256, 0, stream>>>(a2_rows, cur2, N_EDGES);

    scan_kernel<<<1, 1024, 0, stream>>>(cur1, off1);
    scan_kernel<<<1, 1024, 0, stream>>>(cur2, off2);

    scatter_kernel<<<eblocks, 256, 0, stream>>>(a1_rows, a1_cols, a1_vals, cur1, perm1, N_EDGES);
    scatter_kernel<<<eblocks, 256, 0, stream>>>(a2_rows, a2_cols, a2_vals, cur2, perm2, N_EDGES);

    const int rblocks = (N_NODES * 64) / 256;   // one wave per row
    csr_spmm_kernel<<<rblocks, 256, 0, stream>>>(off1, perm1, x1, out1);
    csr_spmm_kernel<<<rblocks, 256, 0, stream>>>(off2, perm2, x2, out2);
}